// Round 9
// baseline (856.710 us; speedup 1.0000x reference)
//
#include <hip/hip_runtime.h>
#include <stdint.h>

#define T 4096
#define HDIM 1024
#define FDIM 4096
#define NE 8
#define MAXROWS 10240  // 40 tiles of 256; worst padded total = 8192 + 8*255 = 10232

typedef __bf16 bf16x8 __attribute__((ext_vector_type(8)));
typedef float f32x4 __attribute__((ext_vector_type(4)));

__device__ __forceinline__ unsigned short f2bf(float f) {
    unsigned u = __builtin_bit_cast(unsigned, f);
    u += 0x7FFFu + ((u >> 16) & 1u);   // RNE
    return (unsigned short)(u >> 16);
}

// pack 8 fp32 -> 8 bf16 (native casts; compiler emits v_cvt_pk_bf16_f32, RNE)
__device__ __forceinline__ bf16x8 cvt8(float4 a, float4 b) {
    bf16x8 r;
    r[0] = (__bf16)a.x; r[1] = (__bf16)a.y; r[2] = (__bf16)a.z; r[3] = (__bf16)a.w;
    r[4] = (__bf16)b.x; r[5] = (__bf16)b.y; r[6] = (__bf16)b.z; r[7] = (__bf16)b.w;
    return r;
}

// async 16B/lane global->LDS DMA: lds dest = wave-uniform base + lane*16
__device__ __forceinline__ void cp16(const void* g, const void* lds) {
    __builtin_amdgcn_global_load_lds(
        (const __attribute__((address_space(1))) unsigned int*)g,
        (__attribute__((address_space(3))) unsigned int*)(unsigned int)(unsigned long long)lds,
        16, 0, 0);
}

// ---------------- x -> bf16 (with one extra zero row appended by memset) ----
__global__ void conv_x_k(const float* __restrict__ x, unsigned short* __restrict__ xb) {
    size_t i = ((size_t)blockIdx.x * 256 + threadIdx.x) * 8;
    float4 a = *(const float4*)(x + i);
    float4 b = *(const float4*)(x + i + 4);
    uint4 v;
    v.x = (unsigned)f2bf(a.x) | ((unsigned)f2bf(a.y) << 16);
    v.y = (unsigned)f2bf(a.z) | ((unsigned)f2bf(a.w) << 16);
    v.z = (unsigned)f2bf(b.x) | ((unsigned)f2bf(b.y) << 16);
    v.w = (unsigned)f2bf(b.z) | ((unsigned)f2bf(b.w) << 16);
    *(uint4*)(xb + i) = v;
}

// ---------------- router: logits, top-2, block-aggregated list append --------
// 64 blocks x 1024 threads (16 waves), 64 tokens/block (4 per wave).
// 8 global atomics per block (vs 8192 serial RMWs); positions via LDS atomics.
// List order is permutation-invariant (each row carries token + weight).
__global__ __launch_bounds__(1024) void router_k(
    const float* __restrict__ x, const float* __restrict__ gw,
    float* __restrict__ logits_out, int* __restrict__ cnt,
    int* __restrict__ list, float* __restrict__ wlist) {
    __shared__ int   ltok[128];
    __shared__ int   lexp[128];
    __shared__ float lww[128];
    __shared__ int   lpos[128];
    __shared__ int   bcnt[NE];
    __shared__ int   bbase[NE];

    int tid = threadIdx.x, wave = tid >> 6, lane = tid & 63;
    if (tid < NE) bcnt[tid] = 0;

#pragma unroll 1
    for (int j = 0; j < 4; ++j) {
        int t = blockIdx.x * 64 + wave * 4 + j;
        float acc[NE];
#pragma unroll
        for (int e = 0; e < NE; ++e) acc[e] = 0.f;
        for (int i = 0; i < HDIM / 64; ++i) {
            int h = i * 64 + lane;
            float xv = x[(size_t)t * HDIM + h];
#pragma unroll
            for (int e = 0; e < NE; ++e) acc[e] += xv * gw[e * HDIM + h];
        }
#pragma unroll
        for (int e = 0; e < NE; ++e)
#pragma unroll
            for (int off = 32; off; off >>= 1) acc[e] += __shfl_xor(acc[e], off);
        if (lane == 0) {
#pragma unroll
            for (int e = 0; e < NE; ++e) logits_out[(size_t)t * NE + e] = acc[e];
            int e1 = 0;
#pragma unroll
            for (int e = 1; e < NE; ++e) if (acc[e] > acc[e1]) e1 = e;
            int e2 = (e1 == 0) ? 1 : 0;
#pragma unroll
            for (int e = 0; e < NE; ++e) { if (e == e1) continue; if (acc[e] > acc[e2]) e2 = e; }
            float wa = 1.f / (1.f + expf(acc[e2] - acc[e1]));
            float wb = 1.f - wa;
            int s = (wave * 4 + j) * 2;
            ltok[s] = t;     lexp[s] = e1;     lww[s] = wa;
            ltok[s + 1] = t; lexp[s + 1] = e2; lww[s + 1] = wb;
        }
    }
    __syncthreads();
    if (tid < 128) lpos[tid] = atomicAdd(&bcnt[lexp[tid]], 1);   // LDS atomic
    __syncthreads();
    if (tid < NE) bbase[tid] = atomicAdd(&cnt[tid], bcnt[tid]);  // 8 global atomics
    __syncthreads();
    if (tid < 128) {
        int e = lexp[tid];
        int p = bbase[e] + lpos[tid];
        list[e * T + p] = ltok[tid];
        wlist[e * T + p] = lww[tid];
    }
}

// ---------------- padded exclusive prefix over expert counts (256-aligned) ----
__global__ void offsets_k(const int* __restrict__ cnt, int* __restrict__ poff) {
    if (threadIdx.x == 0) {
        int o = 0; poff[0] = 0;
        for (int e = 0; e < NE; ++e) { o += ((cnt[e] + 255) >> 8) << 8; poff[e + 1] = o; }
    }
}

// ---------------- compact lists into padded row space ----------------
__global__ void compact_k(const int* __restrict__ cnt, const int* __restrict__ poff,
                          const int* __restrict__ list, const float* __restrict__ wlist,
                          int* __restrict__ tok_row, float* __restrict__ w_row) {
    int gid = blockIdx.x * 256 + threadIdx.x;  // NE*T threads
    int e = gid >> 12, i = gid & (T - 1);
    int pc = poff[e + 1] - poff[e];
    if (i < pc) {
        int row = poff[e] + i;
        if (i < cnt[e]) { tok_row[row] = list[e * T + i]; w_row[row] = wlist[e * T + i]; }
        else           { tok_row[row] = T;               w_row[row] = 0.f; }
    }
}

// ---------------- GEMM1: inter = silu(x@w1^T) * (x@w3^T), gathered rows ------
// r3 ring-2 structure (best measured) + FUSED WEIGHT CONVERSION: w1/w3 are
// read fp32 directly (conv_all eliminated, -576MB HBM/iter). B staging is
// T14 reg-staged: issue float4 loads for step k+1 at the TOP of step k (HBM
// latency hides under the 128-MFMA cluster), convert with native bf16 casts
// (v_cvt_pk_bf16_f32, RNE = old f2bf), ds_write_b128 into the SAME swizzled
// layout the ds_reads use. A stays on the cp16 DMA path. One __syncthreads
// per K-step drains both vmcnt and lgkmcnt - sync discipline unchanged.
// Block mapping stays NATURAL (r7 lesson): xcd = bx%8 groups same-weight-
// panel blocks on one XCD; weights dominate traffic.
// LDS tile layout (proven zero-conflict): (row r, chunk cb of 8 bf16) at
//   byte r*128 + ((cb ^ (r&7))*16); write addr = base + lane*16 (2-way
//   aliasing on writes = free, m136).
__global__ __launch_bounds__(512, 2) void gemm1_k(
    const unsigned short* __restrict__ xb, const float* __restrict__ w1,
    const float* __restrict__ w3, const int* __restrict__ tok_row,
    const int* __restrict__ poff, unsigned short* __restrict__ inter, int Fc) {

    __shared__ __align__(16) unsigned short lds[2 * 32768];  // 2 slots x 64KB
    __shared__ int toks[256];
    __shared__ int e_sh;

    int row0 = blockIdx.y * 256;
    if (row0 >= poff[NE]) return;
    int tid = threadIdx.x;
    if (tid == 0) { int e = 0; while (row0 >= poff[e + 1]) ++e; e_sh = e; }
    if (tid < 256) toks[tid] = tok_row[row0 + tid];
    __syncthreads();
    int e = e_sh;
    int fr0 = blockIdx.x * 128;
    const float* w1p = w1 + ((size_t)e * FDIM + fr0) * HDIM;
    const float* w3p = w3 + ((size_t)e * FDIM + fr0) * HDIM;

    int wv = tid >> 6, lane = tid & 63;
    int quad = lane >> 4, l16 = lane & 15;
    int wm = (wv >> 1) * 64;   // 4 wave-rows x 64 rows
    int wn = (wv & 1) * 64;    // 2 wave-cols x 64 f

    // ---- staging geometry: thread -> (8-row group, row sr, swizzled chunk sc)
    int sr = lane >> 3;
    int sc = (lane & 7) ^ sr;           // pre-swizzled global chunk
    unsigned a_off[4];
#pragma unroll
    for (int jj = 0; jj < 4; ++jj)      // A rows: (wv*4+jj)*8 + sr  in 0..255
        a_off[jj] = (unsigned)toks[(wv * 4 + jj) * 8 + sr] * HDIM + sc * 8;
    const float* b1b = w1p + (size_t)(wv * 16 + sr) * HDIM + sc * 8;
    const float* b3b = w3p + (size_t)(wv * 16 + sr) * HDIM + sc * 8;

    char* ldsc = (char*)lds;
    unsigned dstA = (unsigned)(wv * 4) * 1024u;                       // DMA base, + jj*1024
    unsigned wB1  = 32768u + (unsigned)(wv * 2) * 1024u + (unsigned)lane * 16u;  // + jj*1024
    unsigned wB3  = wB1 + 16384u;

    f32x4 acc1[4][4], acc3[4][4];
#pragma unroll
    for (int a = 0; a < 4; ++a)
#pragma unroll
        for (int b = 0; b < 4; ++b) {
            acc1[a][b] = f32x4{0.f, 0.f, 0.f, 0.f};
            acc3[a][b] = f32x4{0.f, 0.f, 0.f, 0.f};
        }

    // ---- prologue: stage K-step 0 into slot 0 ----
#pragma unroll
    for (int jj = 0; jj < 4; ++jj)
        cp16(xb + a_off[jj], ldsc + dstA + jj * 1024);
    {
        float4 p0 = *(const float4*)(b1b);
        float4 p1 = *(const float4*)(b1b + 4);
        float4 p2 = *(const float4*)(b1b + (size_t)8 * HDIM);
        float4 p3 = *(const float4*)(b1b + (size_t)8 * HDIM + 4);
        float4 p4 = *(const float4*)(b3b);
        float4 p5 = *(const float4*)(b3b + 4);
        float4 p6 = *(const float4*)(b3b + (size_t)8 * HDIM);
        float4 p7 = *(const float4*)(b3b + (size_t)8 * HDIM + 4);
        *(bf16x8*)(ldsc + wB1)        = cvt8(p0, p1);
        *(bf16x8*)(ldsc + wB1 + 1024) = cvt8(p2, p3);
        *(bf16x8*)(ldsc + wB3)        = cvt8(p4, p5);
        *(bf16x8*)(ldsc + wB3 + 1024) = cvt8(p6, p7);
    }
    __syncthreads();   // slot 0 resident (vmcnt + lgkm drained)

    // ---- main loop: 16 K-steps, ring-2, ONE barrier per step ----
#pragma unroll 1
    for (int k = 0; k < 16; ++k) {
        const unsigned short* sb = lds + (k & 1) * 32768;   // current slot (shorts)

        // issue next-step loads FIRST: latency hides under this step's MFMAs
        float4 q0, q1, q2, q3, q4, q5, q6, q7;
        if (k < 15) {
            char* db = ldsc + ((k + 1) & 1) * 65536;
            int ko = (k + 1) * 64;
#pragma unroll
            for (int jj = 0; jj < 4; ++jj)
                cp16(xb + a_off[jj] + ko, db + dstA + jj * 1024);
            q0 = *(const float4*)(b1b + ko);
            q1 = *(const float4*)(b1b + ko + 4);
            q2 = *(const float4*)(b1b + (size_t)8 * HDIM + ko);
            q3 = *(const float4*)(b1b + (size_t)8 * HDIM + ko + 4);
            q4 = *(const float4*)(b3b + ko);
            q5 = *(const float4*)(b3b + ko + 4);
            q6 = *(const float4*)(b3b + (size_t)8 * HDIM + ko);
            q7 = *(const float4*)(b3b + (size_t)8 * HDIM + ko + 4);
        }

#pragma unroll
        for (int ks = 0; ks < 2; ++ks) {
            int cb0 = ks * 4 + quad;
            bf16x8 af[4], b1f[4], b3f[4];
#pragma unroll
            for (int mi = 0; mi < 4; ++mi) {
                int m = wm + mi * 16 + l16;
                af[mi] = *(const bf16x8*)(sb + m * 64 + ((cb0 ^ (m & 7)) * 8));
            }
#pragma unroll
            for (int ni = 0; ni < 4; ++ni) {
                int n = wn + ni * 16 + l16;
                int sw = (cb0 ^ (n & 7)) * 8;
                b1f[ni] = *(const bf16x8*)(sb + 16384 + n * 64 + sw);
                b3f[ni] = *(const bf16x8*)(sb + 24576 + n * 64 + sw);
            }
            __builtin_amdgcn_s_setprio(1);
#pragma unroll
            for (int ni = 0; ni < 4; ++ni)
#pragma unroll
                for (int mi = 0; mi < 4; ++mi) {
                    acc1[mi][ni] = __builtin_amdgcn_mfma_f32_16x16x32_bf16(af[mi], b1f[ni], acc1[mi][ni], 0, 0, 0);
                    acc3[mi][ni] = __builtin_amdgcn_mfma_f32_16x16x32_bf16(af[mi], b3f[ni], acc3[mi][ni], 0, 0, 0);
                }
            __builtin_amdgcn_s_setprio(0);
        }

        // convert + publish next-step weights into the other slot
        if (k < 15) {
            char* db = ldsc + ((k + 1) & 1) * 65536;
            *(bf16x8*)(db + wB1)        = cvt8(q0, q1);
            *(bf16x8*)(db + wB1 + 1024) = cvt8(q2, q3);
            *(bf16x8*)(db + wB3)        = cvt8(q4, q5);
            *(bf16x8*)(db + wB3 + 1024) = cvt8(q6, q7);
        }
        // vmcnt+lgkm drain + barrier: publishes slot k+1, protects slot k
        __syncthreads();
    }

    // ---- epilogue: silu(v1)*v3 -> inter ----
#pragma unroll
    for (int mi = 0; mi < 4; ++mi)
#pragma unroll
        for (int ni = 0; ni < 4; ++ni)
#pragma unroll
            for (int r = 0; r < 4; ++r) {
                int m = wm + mi * 16 + quad * 4 + r;
                int n = wn + ni * 16 + l16;
                float v1 = acc1[mi][ni][r], v3 = acc3[mi][ni][r];
                float hval = (v1 / (1.f + __expf(-v1))) * v3;  // silu(v1)*v3
                inter[(size_t)(row0 + m) * Fc + fr0 + n] = f2bf(hval);
            }
}

// ---------------- GEMM2: out[tok] += w_row * (inter @ w2^T) ----------------
// Ring-2 issue-early pipeline + FUSED w2 CONVERSION (fp32 read, reg-staged,
// cvt + ds_write; A=inter stays cp16 DMA). w2 row stride is FDIM (full
// tensor), inter stride Fc. 128x128, 256 thr / 4 waves, 2x32KB LDS ->
// 2 blocks/CU. XCD swizzle kept from r7 (part of its ~20us win).
__global__ __launch_bounds__(256, 2) void gemm2_k(
    const unsigned short* __restrict__ inter, const float* __restrict__ w2,
    const int* __restrict__ tok_row, const float* __restrict__ w_row,
    const int* __restrict__ poff, float* __restrict__ out, int Fc) {

    __shared__ __align__(16) unsigned short lds[2 * 16384];  // 2 slots x 32KB
    __shared__ int e_sh;

    // bijective swizzle: X = by&7 (n-block 0..7), Y = (by>>3)*8 + bx (strip 0..79)
    int bx = blockIdx.x, by = blockIdx.y;
    int Xn = by & 7;
    int Ys = (by >> 3) * 8 + bx;

    int row0 = Ys * 128;
    if (row0 >= poff[NE]) return;
    int tid = threadIdx.x;
    if (tid == 0) { int e = 0; while (row0 >= poff[e + 1]) ++e; e_sh = e; }
    __syncthreads();
    int e = e_sh;
    int n0 = Xn * 128;

    int wv = tid >> 6, lane = tid & 63;
    int quad = lane >> 4, l16 = lane & 15;
    int wm = (wv >> 1) * 64, wn = (wv & 1) * 64;

    int sr = lane >> 3;
    int sc = (lane & 7) ^ sr;
    const unsigned short* a_b = inter + (size_t)(row0 + wv * 32 + sr) * Fc + sc * 8;
    const float* b_b = w2 + ((size_t)e * HDIM + n0 + wv * 32 + sr) * FDIM + sc * 8;

    char* ldsc = (char*)lds;
    unsigned wB = 16384u + (unsigned)(wv * 4) * 1024u + (unsigned)lane * 16u;  // + jj*1024

    f32x4 acc[4][4];
#pragma unroll
    for (int a = 0; a < 4; ++a)
#pragma unroll
        for (int b = 0; b < 4; ++b) acc[a][b] = f32x4{0.f, 0.f, 0.f, 0.f};

    // ---- prologue: stage K-step 0 into slot 0 ----
#pragma unroll
    for (int jj = 0; jj < 4; ++jj)
        cp16(a_b + (size_t)jj * 8 * Fc, ldsc + (wv * 4 + jj) * 1024);
#pragma unroll
    for (int jj = 0; jj < 4; ++jj) {
        float4 p0 = *(const float4*)(b_b + (size_t)jj * 8 * FDIM);
        float4 p1 = *(const float4*)(b_b + (size_t)jj * 8 * FDIM + 4);
        *(bf16x8*)(ldsc + wB + jj * 1024) = cvt8(p0, p1);
    }
    __syncthreads();

    // ---- main loop: Fc/64 K-steps, ring-2, ONE barrier per step ----
    int nk = Fc >> 6;
#pragma unroll 1
    for (int k = 0; k < nk; ++k) {
        const unsigned short* sb = lds + (k & 1) * 16384;   // slot base (shorts)

        float4 q0, q1, q2, q3, q4, q5, q6, q7;
        if (k < nk - 1) {
            char* db = ldsc + ((k + 1) & 1) * 32768;
            int ko = (k + 1) * 64;
#pragma unroll
            for (int jj = 0; jj < 4; ++jj)
                cp16(a_b + (size_t)jj * 8 * Fc + ko, db + (wv * 4 + jj) * 1024);
            q0 = *(const float4*)(b_b + ko);
            q1 = *(const float4*)(b_b + ko + 4);
            q2 = *(const float4*)(b_b + (size_t)8 * FDIM + ko);
            q3 = *(const float4*)(b_b + (size_t)8 * FDIM + ko + 4);
            q4 = *(const float4*)(b_b + (size_t)16 * FDIM + ko);
            q5 = *(const float4*)(b_b + (size_t)16 * FDIM + ko + 4);
            q6 = *(const float4*)(b_b + (size_t)24 * FDIM + ko);
            q7 = *(const float4*)(b_b + (size_t)24 * FDIM + ko + 4);
        }

#pragma unroll
        for (int ks = 0; ks < 2; ++ks) {
            int cb0 = ks * 4 + quad;
            bf16x8 af[4];
#pragma unroll
            for (int mi = 0; mi < 4; ++mi) {
                int m = wm + mi * 16 + l16;
                af[mi] = *(const bf16x8*)(sb + m * 64 + ((cb0 ^ (m & 7)) * 8));
            }
#pragma unroll
            for (int ni = 0; ni < 4; ++ni) {
                int n = wn + ni * 16 + l16;
                bf16x8 bf = *(const bf16x8*)(sb + 8192 + n * 64 + ((cb0 ^ (n & 7)) * 8));
#pragma unroll
                for (int mi = 0; mi < 4; ++mi)
                    acc[mi][ni] = __builtin_amdgcn_mfma_f32_16x16x32_bf16(af[mi], bf, acc[mi][ni], 0, 0, 0);
            }
        }

        if (k < nk - 1) {
            char* db = ldsc + ((k + 1) & 1) * 32768;
            *(bf16x8*)(db + wB)        = cvt8(q0, q1);
            *(bf16x8*)(db + wB + 1024) = cvt8(q2, q3);
            *(bf16x8*)(db + wB + 2048) = cvt8(q4, q5);
            *(bf16x8*)(db + wB + 3072) = cvt8(q6, q7);
        }
        __syncthreads();
    }

#pragma unroll
    for (int mi = 0; mi < 4; ++mi)
#pragma unroll
        for (int r = 0; r < 4; ++r) {
            int m = wm + mi * 16 + quad * 4 + r;
            int grow = row0 + m;
            float wr = w_row[grow];
            if (wr != 0.f) {
                int t = tok_row[grow];
                float* op = out + (size_t)t * HDIM + n0;
#pragma unroll
                for (int ni = 0; ni < 4; ++ni)
                    atomicAdd(op + wn + ni * 16 + l16, wr * acc[mi][ni][r]);
            }
        }
}

extern "C" void kernel_launch(void* const* d_in, const int* in_sizes, int n_in,
                              void* d_out, int out_size, void* d_ws, size_t ws_size,
                              hipStream_t stream) {
    const float* x  = (const float*)d_in[0];
    const float* gw = (const float*)d_in[1];
    const float* w1 = (const float*)d_in[2];
    const float* w2 = (const float*)d_in[3];
    const float* w3 = (const float*)d_in[4];
    float* out = (float*)d_out;
    float* logits = out + (size_t)T * HDIM;

    char* ws = (char*)d_ws;
    size_t off = 0;
    auto alloc = [&](size_t b) {
        off = (off + 255) & ~(size_t)255;
        void* p = ws + off;
        off += b;
        return p;
    };
    int* cnt        = (int*)alloc(NE * 4);
    int* poff       = (int*)alloc((NE + 1) * 4);
    int* list       = (int*)alloc((size_t)NE * T * 4);
    float* wlist    = (float*)alloc((size_t)NE * T * 4);
    int* tok_row    = (int*)alloc(MAXROWS * 4);
    float* w_row    = (float*)alloc(MAXROWS * 4);
    unsigned short* xb = (unsigned short*)alloc((size_t)(T + 1) * HDIM * 2);  // +1 zero row
    size_t fixed_off = off;

    // weights are read fp32 in-kernel now; ws only needs inter
    int Fc = 4096;
    for (;;) {
        size_t need = fixed_off + (size_t)MAXROWS * Fc * 2 + 1024;
        if (need <= ws_size || Fc == 512) break;
        Fc >>= 1;
    }
    unsigned short* inter = (unsigned short*)alloc((size_t)MAXROWS * Fc * 2);

    hipMemsetAsync(cnt, 0, NE * 4, stream);
    hipMemsetAsync(out, 0, (size_t)T * HDIM * 4, stream);
    hipMemsetAsync(xb + (size_t)T * HDIM, 0, HDIM * 2, stream);
    conv_x_k<<<(T * HDIM / 8) / 256, 256, 0, stream>>>(x, xb);
    router_k<<<T / 64, 1024, 0, stream>>>(x, gw, logits, cnt, list, wlist);
    offsets_k<<<1, 64, 0, stream>>>(cnt, poff);
    compact_k<<<NE * T / 256, 256, 0, stream>>>(cnt, poff, list, wlist, tok_row, w_row);

    int nMT1 = MAXROWS / 256;  // 40 strips of 256 for gemm1
    int nMT2 = MAXROWS / 128;  // 80 strips of 128 for gemm2
    for (int f0 = 0; f0 < FDIM; f0 += Fc) {   // single pass when Fc == FDIM
        gemm1_k<<<dim3(Fc / 128, nMT1), 512, 0, stream>>>(
            xb, w1 + (size_t)f0 * HDIM, w3 + (size_t)f0 * HDIM, tok_row, poff, inter, Fc);
        gemm2_k<<<dim3(HDIM / 128, nMT2), 256, 0, stream>>>(
            inter, w2 + f0, tok_row, w_row, poff, out, Fc);
    }
}